// Round 2
// baseline (9816.077 us; speedup 1.0000x reference)
//
#include <hip/hip_runtime.h>

typedef _Float16 f16;
typedef _Float16 f16x8 __attribute__((ext_vector_type(8)));
typedef _Float16 f16x4 __attribute__((ext_vector_type(4)));
typedef float    f32x4 __attribute__((ext_vector_type(4)));

#define NP      82944     // 4*144*144 pixels
#define NPIX_B  20736     // 144*144
#define KP      320       // padded channel dim (300 -> 320)
#define OC      128       // 2*HID
#define NP2     80656     // 4*142*142 head pixels
#define CH      8         // pixel chunks (recurrence is pointwise => chunkable)
#define CHPX    10368     // NP / CH

__device__ __forceinline__ float geluf(float x) {
    return 0.5f * x * (1.0f + erff(x * 0.70710678118654752f));
}
__device__ __forceinline__ float sigm(float x) {
    return 1.0f / (1.0f + __expf(-x));
}
__device__ __forceinline__ f32x4 mfma16(f16x8 a, f16x8 b, f32x4 c) {
    return __builtin_amdgcn_mfma_f32_16x16x32_f16(a, b, c, 0, 0, 0);
}

// ---------------- weight packing ----------------
__global__ __launch_bounds__(64) void pack_gate_w(
    const float* __restrict__ wd2, const float* __restrict__ wfx2, const float* __restrict__ wix2,
    const float* __restrict__ wd1, const float* __restrict__ wfx1, const float* __restrict__ wix1,
    const float* __restrict__ bd2, const float* __restrict__ bfx2, const float* __restrict__ bix2,
    const float* __restrict__ bd1, const float* __restrict__ bfx1, const float* __restrict__ bix1,
    f16* __restrict__ wpk2, f16* __restrict__ wpk1,
    float* __restrict__ bpk2, float* __restrict__ bpk1)
{
    int bid = blockIdx.x;                 // [0, 2*3*320)
    int o = bid % KP;
    int g = (bid / KP) % 3;
    int s = bid / (KP * 3);
    const float* wsrc; const float* bsrc;
    if (s == 0) { wsrc = (g==0)?wd2:((g==1)?wfx2:wix2); bsrc = (g==0)?bd2:((g==1)?bfx2:bix2); }
    else        { wsrc = (g==0)?wd1:((g==1)?wfx1:wix1); bsrc = (g==0)?bd1:((g==1)?bfx1:bix1); }
    f16* wdst = (s==0 ? wpk2 : wpk1) + ((size_t)g*KP + o)*KP;
    int t = threadIdx.x;
#pragma unroll
    for (int i = 0; i < 5; ++i) {
        int k = i*64 + t;
        wdst[k] = (o < 300 && k < 300) ? (f16)wsrc[o*300 + k] : (f16)0.0f;
    }
    if (t == 0) {
        float* bd = (s==0 ? bpk2 : bpk1);
        bd[g*KP + o] = (o < 300) ? bsrc[o] : 0.0f;
    }
}

__global__ __launch_bounds__(64) void pack_line_w(
    const float* __restrict__ lw1, const float* __restrict__ lw2,
    f16* __restrict__ w1p, f16* __restrict__ w2p)
{
    int bid = blockIdx.x;
    int t = threadIdx.x;
    if (bid < 9*OC) {
        int t9 = bid / OC, oc = bid % OC;
        f16* dst = w1p + ((size_t)t9*OC + oc)*KP;
#pragma unroll
        for (int i = 0; i < 5; ++i) {
            int k = i*64 + t;
            dst[k] = (k < 300) ? (f16)lw1[(size_t)(oc*300 + k)*9 + t9] : (f16)0.0f;
        }
    } else {
        int oc = bid - 9*OC;
        f16* dst = w2p + (size_t)oc*OC;
#pragma unroll
        for (int i = 0; i < 2; ++i) {
            int k = i*64 + t;
            dst[k] = (f16)lw2[oc*OC + k];
        }
    }
}

// ---------------- encoder (per chunk): y -> 6 gelu'd 1x1 convs + c/x init ----
__global__ __launch_bounds__(256) void encoder_kernel(
    const float* __restrict__ y,
    const float* __restrict__ w_e1, const float* __restrict__ b_e1,
    const float* __restrict__ w_e2, const float* __restrict__ b_e2,
    const float* __restrict__ w_f1, const float* __restrict__ b_f1,
    const float* __restrict__ w_i1, const float* __restrict__ b_i1,
    const float* __restrict__ w_f2, const float* __restrict__ b_f2,
    const float* __restrict__ w_i2, const float* __restrict__ b_i2,
    f16* __restrict__ enc, float* __restrict__ cbuf, f16* __restrict__ xa,
    int p_off)
{
    int p = blockIdx.x * 256 + threadIdx.x;   // chunk-local pixel
    if (p >= CHPX) return;
    int gp = p_off + p;
    int b = gp / NPIX_B, pin = gp % NPIX_B;
    const float* yb = y + (size_t)b*21*NPIX_B + pin;
    float yv[21];
#pragma unroll
    for (int c = 0; c < 21; ++c) yv[c] = yb[(size_t)c * NPIX_B];

    const float* ws[6] = {w_e1, w_e2, w_f1, w_i1, w_f2, w_i2};
    const float* bs[6] = {b_e1, b_e2, b_f1, b_i1, b_f2, b_i2};

    for (int o = 0; o < 300; o += 4) {
        float g[6][4];
#pragma unroll
        for (int e = 0; e < 6; ++e) {
#pragma unroll
            for (int r = 0; r < 4; ++r) {
                const float* wr = ws[e] + (o + r)*21;
                float acc = bs[e][o + r];
#pragma unroll
                for (int c = 0; c < 21; ++c) acc = fmaf(wr[c], yv[c], acc);
                g[e][r] = geluf(acc);
            }
            f16x4 st;
#pragma unroll
            for (int r = 0; r < 4; ++r) st[r] = (f16)g[e][r];
            *(f16x4*)(enc + (size_t)e*CHPX*KP + (size_t)p*KP + o) = st;
        }
        f32x4 cv; f16x4 xv;
#pragma unroll
        for (int r = 0; r < 4; ++r) {
            float c12 = sigm(g[3][r]) * (-g[0][r]);   // sigmoid(ywiy1) * (-ywe1)
            cv[r] = c12;
            xv[r] = (f16)fmaxf(c12, 0.0f);
        }
        *(f32x4*)(cbuf + (size_t)p*KP + o) = cv;
        *(f16x4*)(xa + (size_t)p*KP + o) = xv;
    }
}

// ---------------- fused gate half-step (per chunk, all indices chunk-local) --
__global__ __launch_bounds__(256) void gate_kernel(
    const f16* __restrict__ xin, const f16* __restrict__ wpk,
    const float* __restrict__ bpk,
    const f16* __restrict__ ey, const f16* __restrict__ fy,
    const f16* __restrict__ iy, const f16* __restrict__ ad,
    float* __restrict__ cio, f16* __restrict__ xout, int first)
{
    int tid = threadIdx.x;
    int l = tid & 63, w = tid >> 6;
    int lr = l & 15, lh = l >> 4;
    int bid = blockIdx.x;
    int mt = bid % 10, nt = bid / 10;
    int o0 = mt * 32;
    int p0 = nt * 128 + w * 32;

    f32x4 acc[3][2][2] = {};
    const f16* bptr0 = xin + (size_t)(p0 + lr)*KP + lh*8;
    const f16* bptr1 = bptr0 + (size_t)16*KP;
    const f16* aptr  = wpk + (size_t)(o0 + lr)*KP + lh*8;

#pragma unroll 2
    for (int k0 = 0; k0 < KP; k0 += 32) {
        f16x8 b0 = *(const f16x8*)(bptr0 + k0);
        f16x8 b1 = *(const f16x8*)(bptr1 + k0);
#pragma unroll
        for (int g = 0; g < 3; ++g) {
#pragma unroll
            for (int m = 0; m < 2; ++m) {
                f16x8 a = *(const f16x8*)(aptr + ((size_t)g*KP + m*16)*KP + k0);
                acc[g][m][0] = mfma16(a, b0, acc[g][m][0]);
                acc[g][m][1] = mfma16(a, b1, acc[g][m][1]);
            }
        }
    }
#pragma unroll
    for (int m = 0; m < 2; ++m) {
        int o = o0 + m*16 + lh*4;
        if (o >= 300) continue;
        f32x4 bd = *(const f32x4*)(bpk + 0*KP + o);
        f32x4 bf = *(const f32x4*)(bpk + 1*KP + o);
        f32x4 bi = *(const f32x4*)(bpk + 2*KP + o);
#pragma unroll
        for (int n = 0; n < 2; ++n) {
            int p = p0 + n*16 + lr;
            size_t base = (size_t)p*KP + o;
            f16x4 vey = *(const f16x4*)(ey + base);
            f16x4 vfy = *(const f16x4*)(fy + base);
            f16x4 viy = *(const f16x4*)(iy + base);
            f32x4 vci = *(const f32x4*)(cio + base);
            f16x4 vad = {};
            if (!first) vad = *(const f16x4*)(ad + base);
            f32x4 co; f16x4 xo;
#pragma unroll
            for (int r = 0; r < 4; ++r) {
                float gd = geluf(acc[0][m][n][r] + bd[r]);
                float gf = geluf(acc[1][m][n][r] + bf[r]);
                float gi = geluf(acc[2][m][n][r] + bi[r]);
                float addv = first ? 0.0f : (float)vad[r];
                float ctl = (float)vey[r] + addv - gd;
                float ft  = sigm(gf + (float)vfy[r]);
                float it  = sigm(gi + (float)viy[r]);
                float ct  = vci[r]*ft + ctl*it;
                co[r] = ct;
                xo[r] = (f16)fmaxf(ct, 0.0f);
            }
            *(f32x4*)(cio + base) = co;     // in-place: same (p,o) read by this thread only
            *(f16x4*)(xout + base) = xo;
        }
    }
}

// ---------------- head: 3x3 valid conv (300->128) + gelu ----------------
__global__ __launch_bounds__(256) void conv3_kernel(
    const f16* __restrict__ xt, const f16* __restrict__ w1p,
    const float* __restrict__ b1, f16* __restrict__ h1)
{
    int tid = threadIdx.x;
    int l = tid & 63, w = tid >> 6;
    int lr = l & 15, lh = l >> 4;
    int bid = blockIdx.x;
    int mtile = bid & 3;
    int xtile = (bid >> 2) & 1;
    int by = bid >> 3;                    // [0, 568)
    int b = by / 142, yy = by % 142;
    int o0 = mtile * 32;
    int xw = xtile * 128 + w * 32;
    if (xw >= 142) return;

    f32x4 acc[2][2] = {};
#pragma unroll 1
    for (int t = 0; t < 9; ++t) {
        int dy = t / 3, dx = t % 3;
        int pbase = (b*144 + yy + dy)*144 + dx + xw + lr;
        int pin0 = min(pbase,      NP - 1);
        int pin1 = min(pbase + 16, NP - 1);
        const f16* bp0 = xt + (size_t)pin0*KP + lh*8;
        const f16* bp1 = xt + (size_t)pin1*KP + lh*8;
        const f16* ap  = w1p + ((size_t)t*OC + o0 + lr)*KP + lh*8;
#pragma unroll 2
        for (int k0 = 0; k0 < KP; k0 += 32) {
            f16x8 b0 = *(const f16x8*)(bp0 + k0);
            f16x8 b1v = *(const f16x8*)(bp1 + k0);
#pragma unroll
            for (int m = 0; m < 2; ++m) {
                f16x8 a = *(const f16x8*)(ap + (size_t)m*16*KP + k0);
                acc[m][0] = mfma16(a, b0,  acc[m][0]);
                acc[m][1] = mfma16(a, b1v, acc[m][1]);
            }
        }
    }
#pragma unroll
    for (int m = 0; m < 2; ++m) {
        int oc = o0 + m*16 + lh*4;
        f32x4 bb = *(const f32x4*)(b1 + oc);
#pragma unroll
        for (int n = 0; n < 2; ++n) {
            int x = xw + n*16 + lr;
            if (x < 142) {
                int pout = (b*142 + yy)*142 + x;
                f16x4 hv;
#pragma unroll
                for (int r = 0; r < 4; ++r) hv[r] = (f16)geluf(acc[m][n][r] + bb[r]);
                *(f16x4*)(h1 + (size_t)pout*OC + oc) = hv;
            }
        }
    }
}

// ---------------- head: 1x1 (128->128) + gelu ----------------
__global__ __launch_bounds__(256) void gemm128_kernel(
    const f16* __restrict__ hin, const f16* __restrict__ w2p,
    const float* __restrict__ b2, f16* __restrict__ hout)
{
    int tid = threadIdx.x;
    int l = tid & 63, w = tid >> 6;
    int lr = l & 15, lh = l >> 4;
    int bid = blockIdx.x;
    int mt = bid & 3, nt = bid >> 2;
    int p0 = nt * 128 + w * 32;
    if (p0 >= NP2) return;
    int o0 = mt * 32;

    f32x4 acc[2][2] = {};
    int pr0 = min(p0 + lr,      NP2 - 1);
    int pr1 = min(p0 + 16 + lr, NP2 - 1);
    const f16* bp0 = hin + (size_t)pr0*OC + lh*8;
    const f16* bp1 = hin + (size_t)pr1*OC + lh*8;
    const f16* ap  = w2p + (size_t)(o0 + lr)*OC + lh*8;
#pragma unroll
    for (int k0 = 0; k0 < OC; k0 += 32) {
        f16x8 b0  = *(const f16x8*)(bp0 + k0);
        f16x8 b1v = *(const f16x8*)(bp1 + k0);
#pragma unroll
        for (int m = 0; m < 2; ++m) {
            f16x8 a = *(const f16x8*)(ap + (size_t)m*16*OC + k0);
            acc[m][0] = mfma16(a, b0,  acc[m][0]);
            acc[m][1] = mfma16(a, b1v, acc[m][1]);
        }
    }
#pragma unroll
    for (int m = 0; m < 2; ++m) {
        int oc = o0 + m*16 + lh*4;
        f32x4 bb = *(const f32x4*)(b2 + oc);
#pragma unroll
        for (int n = 0; n < 2; ++n) {
            int p = p0 + n*16 + lr;
            if (p < NP2) {
                f16x4 hv;
#pragma unroll
                for (int r = 0; r < 4; ++r) hv[r] = (f16)geluf(acc[m][n][r] + bb[r]);
                *(f16x4*)(hout + (size_t)p*OC + oc) = hv;
            }
        }
    }
}

// ---------------- head: 1x1 (128->1) ----------------
__global__ __launch_bounds__(256) void final_dot_kernel(
    const f16* __restrict__ h2, const float* __restrict__ w3,
    const float* __restrict__ b3, float* __restrict__ out)
{
    int p = blockIdx.x * 256 + threadIdx.x;
    if (p >= NP2) return;
    const f16x8* row = (const f16x8*)(h2 + (size_t)p * OC);
    float acc = 0.0f;
#pragma unroll
    for (int i = 0; i < 16; ++i) {
        f16x8 v = row[i];
#pragma unroll
        for (int j = 0; j < 8; ++j) acc = fmaf((float)v[j], w3[i*8 + j], acc);
    }
    out[p] = acc + b3[0];
}

// ---------------- launch ----------------
extern "C" void kernel_launch(void* const* d_in, const int* in_sizes, int n_in,
                              void* d_out, int out_size, void* d_ws, size_t ws_size,
                              hipStream_t stream)
{
    const float* y      = (const float*)d_in[0];
    const float* we1_w  = (const float*)d_in[1];  const float* we1_b  = (const float*)d_in[2];
    const float* we2_w  = (const float*)d_in[3];  const float* we2_b  = (const float*)d_in[4];
    const float* wfy1_w = (const float*)d_in[5];  const float* wfy1_b = (const float*)d_in[6];
    const float* wiy1_w = (const float*)d_in[7];  const float* wiy1_b = (const float*)d_in[8];
    const float* wfy2_w = (const float*)d_in[9];  const float* wfy2_b = (const float*)d_in[10];
    const float* wiy2_w = (const float*)d_in[11]; const float* wiy2_b = (const float*)d_in[12];
    const float* wd1_w  = (const float*)d_in[13]; const float* wd1_b  = (const float*)d_in[14];
    const float* wd2_w  = (const float*)d_in[15]; const float* wd2_b  = (const float*)d_in[16];
    const float* wfx1_w = (const float*)d_in[17]; const float* wfx1_b = (const float*)d_in[18];
    const float* wix1_w = (const float*)d_in[19]; const float* wix1_b = (const float*)d_in[20];
    const float* wfx2_w = (const float*)d_in[21]; const float* wfx2_b = (const float*)d_in[22];
    const float* wix2_w = (const float*)d_in[23]; const float* wix2_b = (const float*)d_in[24];
    const float* line_w1 = (const float*)d_in[25]; const float* line_b1 = (const float*)d_in[26];
    const float* line_w2 = (const float*)d_in[27]; const float* line_b2 = (const float*)d_in[28];
    const float* line_w3 = (const float*)d_in[29]; const float* line_b3 = (const float*)d_in[30];
    float* out = (float*)d_out;

    char* base = (char*)d_ws;
    size_t off = 0;
    auto take = [&](size_t bytes) -> void* {
        void* r = base + off;
        off += (bytes + 255) & ~(size_t)255;
        return r;
    };
    // ---- chunk-local recurrence buffers (reused across 8 chunks) ----
    char* chunk_base = base;
    f16*   enc  = (f16*)take((size_t)6 * CHPX * KP * sizeof(f16));   // 39.8 MB
    f16*   xa   = (f16*)take((size_t)CHPX * KP * sizeof(f16));       //  6.6 MB
    f16*   xb   = (f16*)take((size_t)CHPX * KP * sizeof(f16));       //  6.6 MB
    float* cbuf = (float*)take((size_t)CHPX * KP * sizeof(float));   // 13.3 MB
    // ---- persistent ----
    f16* xt1full = (f16*)take((size_t)NP * KP * sizeof(f16));        // 53.1 MB
    f16* wpk2 = (f16*)take((size_t)3 * KP * KP * sizeof(f16));
    f16* wpk1 = (f16*)take((size_t)3 * KP * KP * sizeof(f16));
    float* bpk2 = (float*)take((size_t)3 * KP * sizeof(float));
    float* bpk1 = (float*)take((size_t)3 * KP * sizeof(float));
    f16* w1p = (f16*)take((size_t)9 * OC * KP * sizeof(f16));
    f16* w2p = (f16*)take((size_t)OC * OC * sizeof(f16));
    // h1/h2 alias the (then-dead) chunk region: 41.3 MB <= 66.3 MB
    f16* h1 = (f16*)chunk_base;
    f16* h2 = (f16*)(chunk_base + (size_t)NP2 * OC * sizeof(f16));
    if (off > ws_size) return;   // ~122 MB required; fail loudly via absmax

    pack_gate_w<<<2*3*KP, 64, 0, stream>>>(wd2_w, wfx2_w, wix2_w, wd1_w, wfx1_w, wix1_w,
                                           wd2_b, wfx2_b, wix2_b, wd1_b, wfx1_b, wix1_b,
                                           wpk2, wpk1, bpk2, bpk1);
    pack_line_w<<<9*OC + OC, 64, 0, stream>>>(line_w1, line_w2, w1p, w2p);

    const int EGRID = (CHPX + 255) / 256;       // 41
    const int GGRID = (CHPX / 128) * 10;        // 810
    f16* e0 = enc + (size_t)0*CHPX*KP;  // ywe1
    f16* e1 = enc + (size_t)1*CHPX*KP;  // ywe2
    f16* e2 = enc + (size_t)2*CHPX*KP;  // ywfy1
    f16* e3 = enc + (size_t)3*CHPX*KP;  // ywiy1
    f16* e4 = enc + (size_t)4*CHPX*KP;  // ywfy2
    f16* e5 = enc + (size_t)5*CHPX*KP;  // ywiy2

    for (int c = 0; c < CH; ++c) {
        int p_off = c * CHPX;
        encoder_kernel<<<EGRID, 256, 0, stream>>>(y,
            we1_w, we1_b, we2_w, we2_b, wfy1_w, wfy1_b, wiy1_w, wiy1_b,
            wfy2_w, wfy2_b, wiy2_w, wiy2_b,
            enc, cbuf, xa, p_off);

        // step2 #1 (xt1 term == 0): xa -> xb
        gate_kernel<<<GGRID, 256, 0, stream>>>(xa, wpk2, bpk2, e1, e4, e5, xb, cbuf, xb, 1);
        for (int it = 0; it < 3; ++it) {
            // step1: xb -> xa  (add term = xb)
            gate_kernel<<<GGRID, 256, 0, stream>>>(xb, wpk1, bpk1, e0, e2, e3, xb, cbuf, xa, 0);
            // step2: xa -> xb (add term = xb); last one writes final xt1
            f16* xo = (it == 2) ? (xt1full + (size_t)p_off * KP) : xb;
            gate_kernel<<<GGRID, 256, 0, stream>>>(xa, wpk2, bpk2, e1, e4, e5, xb, cbuf, xo, 0);
        }
    }

    conv3_kernel<<<568*2*4, 256, 0, stream>>>(xt1full, w1p, line_b1, h1);
    gemm128_kernel<<<((NP2 + 127)/128) * 4, 256, 0, stream>>>(h1, w2p, line_b2, h2);
    final_dot_kernel<<<(NP2 + 255)/256, 256, 0, stream>>>(h2, line_w3, line_b3, out);
}

// Round 3
// 4652.128 us; speedup vs baseline: 2.1100x; 2.1100x over previous
//
#include <hip/hip_runtime.h>

typedef _Float16 f16;
typedef _Float16 f16x8 __attribute__((ext_vector_type(8)));
typedef _Float16 f16x4 __attribute__((ext_vector_type(4)));
typedef float    f32x4 __attribute__((ext_vector_type(4)));

#define NP      82944     // 4*144*144 pixels
#define NPIX_B  20736     // 144*144
#define KP      320       // padded channel dim (300 -> 320)
#define OC      128       // 2*HID
#define NP2     80656     // 4*142*142 head pixels
#define CH      8         // pixel chunks (recurrence is pointwise => chunkable)
#define CHPX    10368     // NP / CH
#define NOC     15        // encoder o-chunks
#define OCH     20        // outputs per o-chunk (15*20 = 300)

__device__ __forceinline__ float geluf(float x) {
    return 0.5f * x * (1.0f + erff(x * 0.70710678118654752f));
}
__device__ __forceinline__ float sigm(float x) {
    return 1.0f / (1.0f + __expf(-x));
}
__device__ __forceinline__ f32x4 mfma16(f16x8 a, f16x8 b, f32x4 c) {
    return __builtin_amdgcn_mfma_f32_16x16x32_f16(a, b, c, 0, 0, 0);
}

// ---------------- weight packing ----------------
__global__ __launch_bounds__(64) void pack_gate_w(
    const float* __restrict__ wd2, const float* __restrict__ wfx2, const float* __restrict__ wix2,
    const float* __restrict__ wd1, const float* __restrict__ wfx1, const float* __restrict__ wix1,
    const float* __restrict__ bd2, const float* __restrict__ bfx2, const float* __restrict__ bix2,
    const float* __restrict__ bd1, const float* __restrict__ bfx1, const float* __restrict__ bix1,
    f16* __restrict__ wpk2, f16* __restrict__ wpk1,
    float* __restrict__ bpk2, float* __restrict__ bpk1)
{
    int bid = blockIdx.x;                 // [0, 2*3*320)
    int o = bid % KP;
    int g = (bid / KP) % 3;
    int s = bid / (KP * 3);
    const float* wsrc; const float* bsrc;
    if (s == 0) { wsrc = (g==0)?wd2:((g==1)?wfx2:wix2); bsrc = (g==0)?bd2:((g==1)?bfx2:bix2); }
    else        { wsrc = (g==0)?wd1:((g==1)?wfx1:wix1); bsrc = (g==0)?bd1:((g==1)?bfx1:bix1); }
    f16* wdst = (s==0 ? wpk2 : wpk1) + ((size_t)g*KP + o)*KP;
    int t = threadIdx.x;
#pragma unroll
    for (int i = 0; i < 5; ++i) {
        int k = i*64 + t;
        wdst[k] = (o < 300 && k < 300) ? (f16)wsrc[o*300 + k] : (f16)0.0f;
    }
    if (t == 0) {
        float* bd = (s==0 ? bpk2 : bpk1);
        bd[g*KP + o] = (o < 300) ? bsrc[o] : 0.0f;
    }
}

__global__ __launch_bounds__(64) void pack_line_w(
    const float* __restrict__ lw1, const float* __restrict__ lw2,
    f16* __restrict__ w1p, f16* __restrict__ w2p)
{
    int bid = blockIdx.x;
    int t = threadIdx.x;
    if (bid < 9*OC) {
        int t9 = bid / OC, oc = bid % OC;
        f16* dst = w1p + ((size_t)t9*OC + oc)*KP;
#pragma unroll
        for (int i = 0; i < 5; ++i) {
            int k = i*64 + t;
            dst[k] = (k < 300) ? (f16)lw1[(size_t)(oc*300 + k)*9 + t9] : (f16)0.0f;
        }
    } else {
        int oc = bid - 9*OC;
        f16* dst = w2p + (size_t)oc*OC;
#pragma unroll
        for (int i = 0; i < 2; ++i) {
            int k = i*64 + t;
            dst[k] = (f16)lw2[oc*OC + k];
        }
    }
}

// ---------------- encoder (per chunk, o-split): y -> 6 gelu'd 1x1 convs -----
// grid = ceil(CHPX/256) * NOC; block (pb, oc) handles 256 pixels x 20 outputs.
// c12/x12 init re-reads the just-written e0/e3 rows (same thread, cache-hot).
__global__ __launch_bounds__(256) void encoder_kernel(
    const float* __restrict__ y,
    const float* __restrict__ w_e1, const float* __restrict__ b_e1,
    const float* __restrict__ w_e2, const float* __restrict__ b_e2,
    const float* __restrict__ w_f1, const float* __restrict__ b_f1,
    const float* __restrict__ w_i1, const float* __restrict__ b_i1,
    const float* __restrict__ w_f2, const float* __restrict__ b_f2,
    const float* __restrict__ w_i2, const float* __restrict__ b_i2,
    f16* __restrict__ enc, float* __restrict__ cbuf, f16* __restrict__ xa,
    int p_off)
{
    int oc = blockIdx.x % NOC;
    int pb = blockIdx.x / NOC;
    int p  = pb * 256 + threadIdx.x;      // chunk-local pixel
    if (p >= CHPX) return;
    int o0 = oc * OCH;
    int gp = p_off + p;
    int b = gp / NPIX_B, pin = gp % NPIX_B;
    const float* yb = y + (size_t)b*21*NPIX_B + pin;
    float yv[21];
#pragma unroll
    for (int c = 0; c < 21; ++c) yv[c] = yb[(size_t)c * NPIX_B];

    size_t rowbase = (size_t)p*KP + o0;

#define ENC_ONE(W, B, EIDX)                                            \
    {                                                                  \
        f16* dst = enc + (size_t)(EIDX)*CHPX*KP + rowbase;             \
        _Pragma("unroll 1")                                            \
        for (int rq = 0; rq < 5; ++rq) {                               \
            f16x4 st;                                                  \
            _Pragma("unroll")                                          \
            for (int j = 0; j < 4; ++j) {                              \
                int r = rq*4 + j;                                      \
                const float* wr = (W) + (o0 + r)*21;                   \
                float acc = (B)[o0 + r];                               \
                _Pragma("unroll")                                      \
                for (int c = 0; c < 21; ++c) acc = fmaf(wr[c], yv[c], acc); \
                st[j] = (f16)geluf(acc);                               \
            }                                                          \
            *(f16x4*)(dst + rq*4) = st;                                \
        }                                                              \
    }

    ENC_ONE(w_e1, b_e1, 0)
    ENC_ONE(w_e2, b_e2, 1)
    ENC_ONE(w_f1, b_f1, 2)
    ENC_ONE(w_i1, b_i1, 3)
    ENC_ONE(w_f2, b_f2, 4)
    ENC_ONE(w_i2, b_i2, 5)
#undef ENC_ONE

    // c12 = sigmoid(ywiy1) * (-ywe1);  x12 = relu(c12)
#pragma unroll 1
    for (int rq = 0; rq < 5; ++rq) {
        f16x4 v0 = *(const f16x4*)(enc + (size_t)0*CHPX*KP + rowbase + rq*4);
        f16x4 v3 = *(const f16x4*)(enc + (size_t)3*CHPX*KP + rowbase + rq*4);
        f32x4 cv; f16x4 xv;
#pragma unroll
        for (int j = 0; j < 4; ++j) {
            float c12 = sigm((float)v3[j]) * (-(float)v0[j]);
            cv[j] = c12;
            xv[j] = (f16)fmaxf(c12, 0.0f);
        }
        *(f32x4*)(cbuf + rowbase + rq*4) = cv;
        *(f16x4*)(xa + rowbase + rq*4) = xv;
    }
}

// ---------------- fused gate half-step (per chunk, all indices chunk-local) --
__global__ __launch_bounds__(256) void gate_kernel(
    const f16* __restrict__ xin, const f16* __restrict__ wpk,
    const float* __restrict__ bpk,
    const f16* __restrict__ ey, const f16* __restrict__ fy,
    const f16* __restrict__ iy, const f16* __restrict__ ad,
    float* __restrict__ cio, f16* __restrict__ xout, int first)
{
    int tid = threadIdx.x;
    int l = tid & 63, w = tid >> 6;
    int lr = l & 15, lh = l >> 4;
    int bid = blockIdx.x;
    int mt = bid % 10, nt = bid / 10;
    int o0 = mt * 32;
    int p0 = nt * 128 + w * 32;

    f32x4 acc[3][2][2] = {};
    const f16* bptr0 = xin + (size_t)(p0 + lr)*KP + lh*8;
    const f16* bptr1 = bptr0 + (size_t)16*KP;
    const f16* aptr  = wpk + (size_t)(o0 + lr)*KP + lh*8;

#pragma unroll 2
    for (int k0 = 0; k0 < KP; k0 += 32) {
        f16x8 b0 = *(const f16x8*)(bptr0 + k0);
        f16x8 b1 = *(const f16x8*)(bptr1 + k0);
#pragma unroll
        for (int g = 0; g < 3; ++g) {
#pragma unroll
            for (int m = 0; m < 2; ++m) {
                f16x8 a = *(const f16x8*)(aptr + ((size_t)g*KP + m*16)*KP + k0);
                acc[g][m][0] = mfma16(a, b0, acc[g][m][0]);
                acc[g][m][1] = mfma16(a, b1, acc[g][m][1]);
            }
        }
    }
#pragma unroll
    for (int m = 0; m < 2; ++m) {
        int o = o0 + m*16 + lh*4;
        if (o >= 300) continue;
        f32x4 bd = *(const f32x4*)(bpk + 0*KP + o);
        f32x4 bf = *(const f32x4*)(bpk + 1*KP + o);
        f32x4 bi = *(const f32x4*)(bpk + 2*KP + o);
#pragma unroll
        for (int n = 0; n < 2; ++n) {
            int p = p0 + n*16 + lr;
            size_t base = (size_t)p*KP + o;
            f16x4 vey = *(const f16x4*)(ey + base);
            f16x4 vfy = *(const f16x4*)(fy + base);
            f16x4 viy = *(const f16x4*)(iy + base);
            f32x4 vci = *(const f32x4*)(cio + base);
            f16x4 vad = {};
            if (!first) vad = *(const f16x4*)(ad + base);
            f32x4 co; f16x4 xo;
#pragma unroll
            for (int r = 0; r < 4; ++r) {
                float gd = geluf(acc[0][m][n][r] + bd[r]);
                float gf = geluf(acc[1][m][n][r] + bf[r]);
                float gi = geluf(acc[2][m][n][r] + bi[r]);
                float addv = first ? 0.0f : (float)vad[r];
                float ctl = (float)vey[r] + addv - gd;
                float ft  = sigm(gf + (float)vfy[r]);
                float it  = sigm(gi + (float)viy[r]);
                float ct  = vci[r]*ft + ctl*it;
                co[r] = ct;
                xo[r] = (f16)fmaxf(ct, 0.0f);
            }
            *(f32x4*)(cio + base) = co;     // in-place: same (p,o) read by this thread only
            *(f16x4*)(xout + base) = xo;
        }
    }
}

// ---------------- head: 3x3 valid conv (300->128) + gelu ----------------
__global__ __launch_bounds__(256) void conv3_kernel(
    const f16* __restrict__ xt, const f16* __restrict__ w1p,
    const float* __restrict__ b1, f16* __restrict__ h1)
{
    int tid = threadIdx.x;
    int l = tid & 63, w = tid >> 6;
    int lr = l & 15, lh = l >> 4;
    int bid = blockIdx.x;
    int mtile = bid & 3;
    int xtile = (bid >> 2) & 1;
    int by = bid >> 3;                    // [0, 568)
    int b = by / 142, yy = by % 142;
    int o0 = mtile * 32;
    int xw = xtile * 128 + w * 32;
    if (xw >= 142) return;

    f32x4 acc[2][2] = {};
#pragma unroll 1
    for (int t = 0; t < 9; ++t) {
        int dy = t / 3, dx = t % 3;
        int pbase = (b*144 + yy + dy)*144 + dx + xw + lr;
        int pin0 = min(pbase,      NP - 1);
        int pin1 = min(pbase + 16, NP - 1);
        const f16* bp0 = xt + (size_t)pin0*KP + lh*8;
        const f16* bp1 = xt + (size_t)pin1*KP + lh*8;
        const f16* ap  = w1p + ((size_t)t*OC + o0 + lr)*KP + lh*8;
#pragma unroll 2
        for (int k0 = 0; k0 < KP; k0 += 32) {
            f16x8 b0 = *(const f16x8*)(bp0 + k0);
            f16x8 b1v = *(const f16x8*)(bp1 + k0);
#pragma unroll
            for (int m = 0; m < 2; ++m) {
                f16x8 a = *(const f16x8*)(ap + (size_t)m*16*KP + k0);
                acc[m][0] = mfma16(a, b0,  acc[m][0]);
                acc[m][1] = mfma16(a, b1v, acc[m][1]);
            }
        }
    }
#pragma unroll
    for (int m = 0; m < 2; ++m) {
        int oc = o0 + m*16 + lh*4;
        f32x4 bb = *(const f32x4*)(b1 + oc);
#pragma unroll
        for (int n = 0; n < 2; ++n) {
            int x = xw + n*16 + lr;
            if (x < 142) {
                int pout = (b*142 + yy)*142 + x;
                f16x4 hv;
#pragma unroll
                for (int r = 0; r < 4; ++r) hv[r] = (f16)geluf(acc[m][n][r] + bb[r]);
                *(f16x4*)(h1 + (size_t)pout*OC + oc) = hv;
            }
        }
    }
}

// ---------------- head: 1x1 (128->128) + gelu ----------------
__global__ __launch_bounds__(256) void gemm128_kernel(
    const f16* __restrict__ hin, const f16* __restrict__ w2p,
    const float* __restrict__ b2, f16* __restrict__ hout)
{
    int tid = threadIdx.x;
    int l = tid & 63, w = tid >> 6;
    int lr = l & 15, lh = l >> 4;
    int bid = blockIdx.x;
    int mt = bid & 3, nt = bid >> 2;
    int p0 = nt * 128 + w * 32;
    if (p0 >= NP2) return;
    int o0 = mt * 32;

    f32x4 acc[2][2] = {};
    int pr0 = min(p0 + lr,      NP2 - 1);
    int pr1 = min(p0 + 16 + lr, NP2 - 1);
    const f16* bp0 = hin + (size_t)pr0*OC + lh*8;
    const f16* bp1 = hin + (size_t)pr1*OC + lh*8;
    const f16* ap  = w2p + (size_t)(o0 + lr)*OC + lh*8;
#pragma unroll
    for (int k0 = 0; k0 < OC; k0 += 32) {
        f16x8 b0  = *(const f16x8*)(bp0 + k0);
        f16x8 b1v = *(const f16x8*)(bp1 + k0);
#pragma unroll
        for (int m = 0; m < 2; ++m) {
            f16x8 a = *(const f16x8*)(ap + (size_t)m*16*OC + k0);
            acc[m][0] = mfma16(a, b0,  acc[m][0]);
            acc[m][1] = mfma16(a, b1v, acc[m][1]);
        }
    }
#pragma unroll
    for (int m = 0; m < 2; ++m) {
        int oc = o0 + m*16 + lh*4;
        f32x4 bb = *(const f32x4*)(b2 + oc);
#pragma unroll
        for (int n = 0; n < 2; ++n) {
            int p = p0 + n*16 + lr;
            if (p < NP2) {
                f16x4 hv;
#pragma unroll
                for (int r = 0; r < 4; ++r) hv[r] = (f16)geluf(acc[m][n][r] + bb[r]);
                *(f16x4*)(hout + (size_t)p*OC + oc) = hv;
            }
        }
    }
}

// ---------------- head: 1x1 (128->1) ----------------
__global__ __launch_bounds__(256) void final_dot_kernel(
    const f16* __restrict__ h2, const float* __restrict__ w3,
    const float* __restrict__ b3, float* __restrict__ out)
{
    int p = blockIdx.x * 256 + threadIdx.x;
    if (p >= NP2) return;
    const f16x8* row = (const f16x8*)(h2 + (size_t)p * OC);
    float acc = 0.0f;
#pragma unroll
    for (int i = 0; i < 16; ++i) {
        f16x8 v = row[i];
#pragma unroll
        for (int j = 0; j < 8; ++j) acc = fmaf((float)v[j], w3[i*8 + j], acc);
    }
    out[p] = acc + b3[0];
}

// ---------------- launch ----------------
extern "C" void kernel_launch(void* const* d_in, const int* in_sizes, int n_in,
                              void* d_out, int out_size, void* d_ws, size_t ws_size,
                              hipStream_t stream)
{
    const float* y      = (const float*)d_in[0];
    const float* we1_w  = (const float*)d_in[1];  const float* we1_b  = (const float*)d_in[2];
    const float* we2_w  = (const float*)d_in[3];  const float* we2_b  = (const float*)d_in[4];
    const float* wfy1_w = (const float*)d_in[5];  const float* wfy1_b = (const float*)d_in[6];
    const float* wiy1_w = (const float*)d_in[7];  const float* wiy1_b = (const float*)d_in[8];
    const float* wfy2_w = (const float*)d_in[9];  const float* wfy2_b = (const float*)d_in[10];
    const float* wiy2_w = (const float*)d_in[11]; const float* wiy2_b = (const float*)d_in[12];
    const float* wd1_w  = (const float*)d_in[13]; const float* wd1_b  = (const float*)d_in[14];
    const float* wd2_w  = (const float*)d_in[15]; const float* wd2_b  = (const float*)d_in[16];
    const float* wfx1_w = (const float*)d_in[17]; const float* wfx1_b = (const float*)d_in[18];
    const float* wix1_w = (const float*)d_in[19]; const float* wix1_b = (const float*)d_in[20];
    const float* wfx2_w = (const float*)d_in[21]; const float* wfx2_b = (const float*)d_in[22];
    const float* wix2_w = (const float*)d_in[23]; const float* wix2_b = (const float*)d_in[24];
    const float* line_w1 = (const float*)d_in[25]; const float* line_b1 = (const float*)d_in[26];
    const float* line_w2 = (const float*)d_in[27]; const float* line_b2 = (const float*)d_in[28];
    const float* line_w3 = (const float*)d_in[29]; const float* line_b3 = (const float*)d_in[30];
    float* out = (float*)d_out;

    char* base = (char*)d_ws;
    size_t off = 0;
    auto take = [&](size_t bytes) -> void* {
        void* r = base + off;
        off += (bytes + 255) & ~(size_t)255;
        return r;
    };
    // ---- chunk-local recurrence buffers (reused across 8 chunks) ----
    char* chunk_base = base;
    f16*   enc  = (f16*)take((size_t)6 * CHPX * KP * sizeof(f16));   // 39.8 MB
    f16*   xa   = (f16*)take((size_t)CHPX * KP * sizeof(f16));       //  6.6 MB
    f16*   xb   = (f16*)take((size_t)CHPX * KP * sizeof(f16));       //  6.6 MB
    float* cbuf = (float*)take((size_t)CHPX * KP * sizeof(float));   // 13.3 MB
    // ---- persistent ----
    f16* xt1full = (f16*)take((size_t)NP * KP * sizeof(f16));        // 53.1 MB
    f16* wpk2 = (f16*)take((size_t)3 * KP * KP * sizeof(f16));
    f16* wpk1 = (f16*)take((size_t)3 * KP * KP * sizeof(f16));
    float* bpk2 = (float*)take((size_t)3 * KP * sizeof(float));
    float* bpk1 = (float*)take((size_t)3 * KP * sizeof(float));
    f16* w1p = (f16*)take((size_t)9 * OC * KP * sizeof(f16));
    f16* w2p = (f16*)take((size_t)OC * OC * sizeof(f16));
    // h1/h2 alias the (then-dead) chunk region: 41.3 MB <= 66.3 MB
    f16* h1 = (f16*)chunk_base;
    f16* h2 = (f16*)(chunk_base + (size_t)NP2 * OC * sizeof(f16));
    if (off > ws_size) return;   // ~122 MB required; fail loudly via absmax

    pack_gate_w<<<2*3*KP, 64, 0, stream>>>(wd2_w, wfx2_w, wix2_w, wd1_w, wfx1_w, wix1_w,
                                           wd2_b, wfx2_b, wix2_b, wd1_b, wfx1_b, wix1_b,
                                           wpk2, wpk1, bpk2, bpk1);
    pack_line_w<<<9*OC + OC, 64, 0, stream>>>(line_w1, line_w2, w1p, w2p);

    const int EGRID = ((CHPX + 255) / 256) * NOC;   // 41 * 15 = 615
    const int GGRID = (CHPX / 128) * 10;            // 810
    f16* e0 = enc + (size_t)0*CHPX*KP;  // ywe1
    f16* e1 = enc + (size_t)1*CHPX*KP;  // ywe2
    f16* e2 = enc + (size_t)2*CHPX*KP;  // ywfy1
    f16* e3 = enc + (size_t)3*CHPX*KP;  // ywiy1
    f16* e4 = enc + (size_t)4*CHPX*KP;  // ywfy2
    f16* e5 = enc + (size_t)5*CHPX*KP;  // ywiy2

    for (int c = 0; c < CH; ++c) {
        int p_off = c * CHPX;
        encoder_kernel<<<EGRID, 256, 0, stream>>>(y,
            we1_w, we1_b, we2_w, we2_b, wfy1_w, wfy1_b, wiy1_w, wiy1_b,
            wfy2_w, wfy2_b, wiy2_w, wiy2_b,
            enc, cbuf, xa, p_off);

        // step2 #1 (xt1 term == 0): xa -> xb
        gate_kernel<<<GGRID, 256, 0, stream>>>(xa, wpk2, bpk2, e1, e4, e5, xb, cbuf, xb, 1);
        for (int it = 0; it < 3; ++it) {
            // step1: xb -> xa  (add term = xb)
            gate_kernel<<<GGRID, 256, 0, stream>>>(xb, wpk1, bpk1, e0, e2, e3, xb, cbuf, xa, 0);
            // step2: xa -> xb (add term = xb); last one writes final xt1
            f16* xo = (it == 2) ? (xt1full + (size_t)p_off * KP) : xb;
            gate_kernel<<<GGRID, 256, 0, stream>>>(xa, wpk2, bpk2, e1, e4, e5, xb, cbuf, xo, 0);
        }
    }

    conv3_kernel<<<568*2*4, 256, 0, stream>>>(xt1full, w1p, line_b1, h1);
    gemm128_kernel<<<((NP2 + 127)/128) * 4, 256, 0, stream>>>(h1, w2p, line_b2, h2);
    final_dot_kernel<<<(NP2 + 255)/256, 256, 0, stream>>>(h2, line_w3, line_b3, out);
}

// Round 4
// 3077.635 us; speedup vs baseline: 3.1895x; 1.5116x over previous
//
#include <hip/hip_runtime.h>

typedef _Float16 f16;
typedef _Float16 f16x8 __attribute__((ext_vector_type(8)));
typedef _Float16 f16x4 __attribute__((ext_vector_type(4)));
typedef float    f32x4 __attribute__((ext_vector_type(4)));

#define NP      82944     // 4*144*144 pixels
#define NPIX_B  20736     // 144*144
#define KP      320       // padded channel dim (300 -> 320)
#define OC      128       // 2*HID
#define NP2     80656     // 4*142*142 head pixels
#define CH      8         // pixel chunks (recurrence is pointwise => chunkable)
#define CHPX    10368     // NP / CH
#define NOC     15        // encoder o-chunks
#define OCH     20        // outputs per o-chunk (15*20 = 300)

__device__ __forceinline__ float geluf(float x) {
    return 0.5f * x * (1.0f + erff(x * 0.70710678118654752f));
}
__device__ __forceinline__ float sigm(float x) {
    return 1.0f / (1.0f + __expf(-x));
}
__device__ __forceinline__ f32x4 mfma16(f16x8 a, f16x8 b, f32x4 c) {
    return __builtin_amdgcn_mfma_f32_16x16x32_f16(a, b, c, 0, 0, 0);
}
__device__ __forceinline__ void gload_lds16(const void* g, void* l) {
    __builtin_amdgcn_global_load_lds(
        (const __attribute__((address_space(1))) void*)g,
        (__attribute__((address_space(3))) void*)l, 16, 0, 0);
}

// ---------------- weight packing ----------------
__global__ __launch_bounds__(64) void pack_gate_w(
    const float* __restrict__ wd2, const float* __restrict__ wfx2, const float* __restrict__ wix2,
    const float* __restrict__ wd1, const float* __restrict__ wfx1, const float* __restrict__ wix1,
    const float* __restrict__ bd2, const float* __restrict__ bfx2, const float* __restrict__ bix2,
    const float* __restrict__ bd1, const float* __restrict__ bfx1, const float* __restrict__ bix1,
    f16* __restrict__ wpk2, f16* __restrict__ wpk1,
    float* __restrict__ bpk2, float* __restrict__ bpk1)
{
    int bid = blockIdx.x;                 // [0, 2*3*320)
    int o = bid % KP;
    int g = (bid / KP) % 3;
    int s = bid / (KP * 3);
    const float* wsrc; const float* bsrc;
    if (s == 0) { wsrc = (g==0)?wd2:((g==1)?wfx2:wix2); bsrc = (g==0)?bd2:((g==1)?bfx2:bix2); }
    else        { wsrc = (g==0)?wd1:((g==1)?wfx1:wix1); bsrc = (g==0)?bd1:((g==1)?bfx1:bix1); }
    f16* wdst = (s==0 ? wpk2 : wpk1) + ((size_t)g*KP + o)*KP;
    int t = threadIdx.x;
#pragma unroll
    for (int i = 0; i < 5; ++i) {
        int k = i*64 + t;
        wdst[k] = (o < 300 && k < 300) ? (f16)wsrc[o*300 + k] : (f16)0.0f;
    }
    if (t == 0) {
        float* bd = (s==0 ? bpk2 : bpk1);
        bd[g*KP + o] = (o < 300) ? bsrc[o] : 0.0f;
    }
}

__global__ __launch_bounds__(64) void pack_line_w(
    const float* __restrict__ lw1, const float* __restrict__ lw2,
    f16* __restrict__ w1p, f16* __restrict__ w2p)
{
    int bid = blockIdx.x;
    int t = threadIdx.x;
    if (bid < 9*OC) {
        int t9 = bid / OC, oc = bid % OC;
        f16* dst = w1p + ((size_t)t9*OC + oc)*KP;
#pragma unroll
        for (int i = 0; i < 5; ++i) {
            int k = i*64 + t;
            dst[k] = (k < 300) ? (f16)lw1[(size_t)(oc*300 + k)*9 + t9] : (f16)0.0f;
        }
    } else {
        int oc = bid - 9*OC;
        f16* dst = w2p + (size_t)oc*OC;
#pragma unroll
        for (int i = 0; i < 2; ++i) {
            int k = i*64 + t;
            dst[k] = (f16)lw2[oc*OC + k];
        }
    }
}

// ---------------- encoder (per chunk, o-split) ----------------
__global__ __launch_bounds__(256) void encoder_kernel(
    const float* __restrict__ y,
    const float* __restrict__ w_e1, const float* __restrict__ b_e1,
    const float* __restrict__ w_e2, const float* __restrict__ b_e2,
    const float* __restrict__ w_f1, const float* __restrict__ b_f1,
    const float* __restrict__ w_i1, const float* __restrict__ b_i1,
    const float* __restrict__ w_f2, const float* __restrict__ b_f2,
    const float* __restrict__ w_i2, const float* __restrict__ b_i2,
    f16* __restrict__ enc, float* __restrict__ cbuf, f16* __restrict__ xa,
    int p_off)
{
    int oc = blockIdx.x % NOC;
    int pb = blockIdx.x / NOC;
    int p  = pb * 256 + threadIdx.x;
    if (p >= CHPX) return;
    int o0 = oc * OCH;
    int gp = p_off + p;
    int b = gp / NPIX_B, pin = gp % NPIX_B;
    const float* yb = y + (size_t)b*21*NPIX_B + pin;
    float yv[21];
#pragma unroll
    for (int c = 0; c < 21; ++c) yv[c] = yb[(size_t)c * NPIX_B];

    size_t rowbase = (size_t)p*KP + o0;

#define ENC_ONE(W, B, EIDX)                                            \
    {                                                                  \
        f16* dst = enc + (size_t)(EIDX)*CHPX*KP + rowbase;             \
        _Pragma("unroll 1")                                            \
        for (int rq = 0; rq < 5; ++rq) {                               \
            f16x4 st;                                                  \
            _Pragma("unroll")                                          \
            for (int j = 0; j < 4; ++j) {                              \
                int r = rq*4 + j;                                      \
                const float* wr = (W) + (o0 + r)*21;                   \
                float acc = (B)[o0 + r];                               \
                _Pragma("unroll")                                      \
                for (int c = 0; c < 21; ++c) acc = fmaf(wr[c], yv[c], acc); \
                st[j] = (f16)geluf(acc);                               \
            }                                                          \
            *(f16x4*)(dst + rq*4) = st;                                \
        }                                                              \
    }

    ENC_ONE(w_e1, b_e1, 0)
    ENC_ONE(w_e2, b_e2, 1)
    ENC_ONE(w_f1, b_f1, 2)
    ENC_ONE(w_i1, b_i1, 3)
    ENC_ONE(w_f2, b_f2, 4)
    ENC_ONE(w_i2, b_i2, 5)
#undef ENC_ONE

#pragma unroll 1
    for (int rq = 0; rq < 5; ++rq) {
        f16x4 v0 = *(const f16x4*)(enc + (size_t)0*CHPX*KP + rowbase + rq*4);
        f16x4 v3 = *(const f16x4*)(enc + (size_t)3*CHPX*KP + rowbase + rq*4);
        f32x4 cv; f16x4 xv;
#pragma unroll
        for (int j = 0; j < 4; ++j) {
            float c12 = sigm((float)v3[j]) * (-(float)v0[j]);
            cv[j] = c12;
            xv[j] = (f16)fmaxf(c12, 0.0f);
        }
        *(f32x4*)(cbuf + rowbase + rq*4) = cv;
        *(f16x4*)(xa + rowbase + rq*4) = xv;
    }
}

// ---------------- fused gate half-step v2: LDS double-buffered MFMA GEMM ----
// Tile: 96 A-rows (3 gates x 32 o) x 256 px, BK=32, 10 ksteps.
// LDS rows padded to 80B (5 x 16B slots; slot 4 = dead pad) -> 2-way banks.
// A region: rows [0,96) at byte row*80; B region: base 7680, rows [0,256).
// Chunk c (16B) maps to lds byte c*16; c<480 -> A(row=c/5,slot=c%5),
// c in [480,1760) -> B. Staged with global_load_lds(16B).
__global__ __launch_bounds__(256) void gate_kernel(
    const f16* __restrict__ xin, const f16* __restrict__ wpk,
    const float* __restrict__ bpk,
    const f16* __restrict__ ey, const f16* __restrict__ fy,
    const f16* __restrict__ iy, const f16* __restrict__ ad,
    float* __restrict__ cio, f16* __restrict__ xout, int first)
{
    __shared__ char smem[2][28160];
    int tid = threadIdx.x;
    int l = tid & 63, w = tid >> 6;
    int lr = l & 15, lh = l >> 4;
    int bid = blockIdx.x;
    int mt = bid % 10, nt = bid / 10;
    int o0 = mt * 32;
    int p0 = nt * 256;

    // per-thread staging source pointers (k0=0); advance by 64B per kstep
    const char* srcb[7];
#pragma unroll
    for (int j = 0; j < 7; ++j) {
        int c = j*256 + tid;
        if (c < 480) {
            int row = c / 5, slot = c % 5; if (slot > 3) slot = 0;
            int g = row >> 5, o = o0 + (row & 31);
            srcb[j] = (const char*)wpk + ((size_t)g*KP + o)*(KP*2) + slot*16;
        } else if (c < 1760) {
            int cb = c - 480;
            int row = cb / 5, slot = cb % 5; if (slot > 3) slot = 0;
            int p = p0 + row; if (p > CHPX-1) p = CHPX-1;
            srcb[j] = (const char*)xin + (size_t)p*(KP*2) + slot*16;
        } else srcb[j] = nullptr;
    }

#define GSTAGE(BUF, KS)                                                \
    {                                                                  \
        int kb = (KS)*64;                                              \
        _Pragma("unroll")                                              \
        for (int j = 0; j < 7; ++j) {                                  \
            int c = j*256 + tid;                                       \
            if (c < 1760)                                              \
                gload_lds16(srcb[j] + kb, &smem[BUF][c*16]);           \
        }                                                              \
    }

    f32x4 acc[3][2][4] = {};
    GSTAGE(0, 0)
    __syncthreads();

    int buf = 0;
#pragma unroll 1
    for (int ks = 0; ks < 10; ++ks) {
        if (ks < 9) { GSTAGE(buf^1, ks+1) }
        f16x8 bfr[4];
#pragma unroll
        for (int n = 0; n < 4; ++n)
            bfr[n] = *(const f16x8*)&smem[buf][7680 + (w*64 + n*16 + lr)*80 + lh*16];
#pragma unroll
        for (int g = 0; g < 3; ++g) {
#pragma unroll
            for (int m = 0; m < 2; ++m) {
                f16x8 a = *(const f16x8*)&smem[buf][(g*32 + m*16 + lr)*80 + lh*16];
#pragma unroll
                for (int n = 0; n < 4; ++n)
                    acc[g][m][n] = mfma16(a, bfr[n], acc[g][m][n]);
            }
        }
        __syncthreads();
        buf ^= 1;
    }

#pragma unroll
    for (int m = 0; m < 2; ++m) {
        int o = o0 + m*16 + lh*4;
        if (o >= 300) continue;
        f32x4 bd = *(const f32x4*)(bpk + 0*KP + o);
        f32x4 bf = *(const f32x4*)(bpk + 1*KP + o);
        f32x4 bi = *(const f32x4*)(bpk + 2*KP + o);
#pragma unroll
        for (int n = 0; n < 4; ++n) {
            int p = p0 + w*64 + n*16 + lr;
            if (p >= CHPX) continue;
            size_t base = (size_t)p*KP + o;
            f16x4 vey = *(const f16x4*)(ey + base);
            f16x4 vfy = *(const f16x4*)(fy + base);
            f16x4 viy = *(const f16x4*)(iy + base);
            f32x4 vci = *(const f32x4*)(cio + base);
            f16x4 vad = {};
            if (!first) vad = *(const f16x4*)(ad + base);
            f32x4 co; f16x4 xo;
#pragma unroll
            for (int r = 0; r < 4; ++r) {
                float gd = geluf(acc[0][m][n][r] + bd[r]);
                float gf = geluf(acc[1][m][n][r] + bf[r]);
                float gi = geluf(acc[2][m][n][r] + bi[r]);
                float addv = first ? 0.0f : (float)vad[r];
                float ctl = (float)vey[r] + addv - gd;
                float ft  = sigm(gf + (float)vfy[r]);
                float it  = sigm(gi + (float)viy[r]);
                float ct  = vci[r]*ft + ctl*it;
                co[r] = ct;
                xo[r] = (f16)fmaxf(ct, 0.0f);
            }
            *(f32x4*)(cio + base) = co;
            *(f16x4*)(xout + base) = xo;
        }
    }
#undef GSTAGE
}

// ---------------- head: 3x3 valid conv v2 (LDS-staged input strip) ----------
// Block: 128 oc x 30 out-px. LDS: 3 rows x 32 px x 320k, row stride 656B
// (41 slots; slot 40 pad). Reads clamp lrow<=95 (invalid outputs discarded).
__global__ __launch_bounds__(256) void conv3_kernel(
    const f16* __restrict__ xt, const f16* __restrict__ w1p,
    const float* __restrict__ b1, f16* __restrict__ h1)
{
    __shared__ char smem[96*656];   // 62.98 KB
    int tid = threadIdx.x;
    int l = tid & 63, w = tid >> 6;
    int lr = l & 15, lh = l >> 4;
    int bid = blockIdx.x;
    int xt5 = bid % 5;
    int by  = bid / 5;              // [0, 568)
    int b = by / 142, yy = by % 142;
    int xw = xt5 * 30;

    // stage 96 rows x 640B
#pragma unroll
    for (int j = 0; j < 16; ++j) {
        int c = j*256 + tid;
        if (c < 3936) {
            int lrow = c / 41, slot = c % 41; if (slot > 39) slot = 39;
            int dy = lrow >> 5, pxo = lrow & 31;
            int gx = xw + pxo; if (gx > 143) gx = 143;
            size_t gp = (size_t)((b*144 + yy + dy)*144 + gx);
            gload_lds16((const char*)xt + gp*(KP*2) + slot*16, &smem[0] + c*16);
        }
    }
    __syncthreads();

    f32x4 acc[2][2] = {};
#pragma unroll 1
    for (int t9 = 0; t9 < 9; ++t9) {
        int dy = t9 / 3, dx = t9 % 3;
        int r0 = dy*32 + dx + lr;        // n=0 row
        int r1 = r0 + 16;                // n=1 row
        if (r1 > 95) r1 = 95;            // clamp (only invalid outputs affected)
        const f16* ap = w1p + ((size_t)(t9*OC + w*32 + lr))*KP + lh*8;
#pragma unroll
        for (int k0 = 0; k0 < KP; k0 += 32) {
            int kb = (k0>>3)*16 + lh*16;
            f16x8 b0 = *(const f16x8*)&smem[r0*656 + kb];
            f16x8 b1 = *(const f16x8*)&smem[r1*656 + kb];
            f16x8 a0 = *(const f16x8*)(ap + k0);
            f16x8 a1 = *(const f16x8*)(ap + (size_t)16*KP + k0);
            acc[0][0] = mfma16(a0, b0, acc[0][0]);
            acc[0][1] = mfma16(a0, b1, acc[0][1]);
            acc[1][0] = mfma16(a1, b0, acc[1][0]);
            acc[1][1] = mfma16(a1, b1, acc[1][1]);
        }
    }
#pragma unroll
    for (int m = 0; m < 2; ++m) {
        int ocb = w*32 + m*16 + lh*4;
        f32x4 bb = *(const f32x4*)(b1 + ocb);
#pragma unroll
        for (int n = 0; n < 2; ++n) {
            int rel = n*16 + lr;
            int x = xw + rel;
            if (rel < 30 && x < 142) {
                int pout = (b*142 + yy)*142 + x;
                f16x4 hv;
#pragma unroll
                for (int r = 0; r < 4; ++r) hv[r] = (f16)geluf(acc[m][n][r] + bb[r]);
                *(f16x4*)(h1 + (size_t)pout*OC + ocb) = hv;
            }
        }
    }
}

// ---------------- head: 1x1 (128->128) + gelu ----------------
__global__ __launch_bounds__(256) void gemm128_kernel(
    const f16* __restrict__ hin, const f16* __restrict__ w2p,
    const float* __restrict__ b2, f16* __restrict__ hout)
{
    int tid = threadIdx.x;
    int l = tid & 63, w = tid >> 6;
    int lr = l & 15, lh = l >> 4;
    int bid = blockIdx.x;
    int mt = bid & 3, nt = bid >> 2;
    int p0 = nt * 128 + w * 32;
    if (p0 >= NP2) return;
    int o0 = mt * 32;

    f32x4 acc[2][2] = {};
    int pr0 = min(p0 + lr,      NP2 - 1);
    int pr1 = min(p0 + 16 + lr, NP2 - 1);
    const f16* bp0 = hin + (size_t)pr0*OC + lh*8;
    const f16* bp1 = hin + (size_t)pr1*OC + lh*8;
    const f16* ap  = w2p + (size_t)(o0 + lr)*OC + lh*8;
#pragma unroll
    for (int k0 = 0; k0 < OC; k0 += 32) {
        f16x8 b0  = *(const f16x8*)(bp0 + k0);
        f16x8 b1v = *(const f16x8*)(bp1 + k0);
#pragma unroll
        for (int m = 0; m < 2; ++m) {
            f16x8 a = *(const f16x8*)(ap + (size_t)m*16*OC + k0);
            acc[m][0] = mfma16(a, b0,  acc[m][0]);
            acc[m][1] = mfma16(a, b1v, acc[m][1]);
        }
    }
#pragma unroll
    for (int m = 0; m < 2; ++m) {
        int oc = o0 + m*16 + lh*4;
        f32x4 bb = *(const f32x4*)(b2 + oc);
#pragma unroll
        for (int n = 0; n < 2; ++n) {
            int p = p0 + n*16 + lr;
            if (p < NP2) {
                f16x4 hv;
#pragma unroll
                for (int r = 0; r < 4; ++r) hv[r] = (f16)geluf(acc[m][n][r] + bb[r]);
                *(f16x4*)(hout + (size_t)p*OC + oc) = hv;
            }
        }
    }
}

// ---------------- head: 1x1 (128->1) ----------------
__global__ __launch_bounds__(256) void final_dot_kernel(
    const f16* __restrict__ h2, const float* __restrict__ w3,
    const float* __restrict__ b3, float* __restrict__ out)
{
    int p = blockIdx.x * 256 + threadIdx.x;
    if (p >= NP2) return;
    const f16x8* row = (const f16x8*)(h2 + (size_t)p * OC);
    float acc = 0.0f;
#pragma unroll
    for (int i = 0; i < 16; ++i) {
        f16x8 v = row[i];
#pragma unroll
        for (int j = 0; j < 8; ++j) acc = fmaf((float)v[j], w3[i*8 + j], acc);
    }
    out[p] = acc + b3[0];
}

// ---------------- launch ----------------
extern "C" void kernel_launch(void* const* d_in, const int* in_sizes, int n_in,
                              void* d_out, int out_size, void* d_ws, size_t ws_size,
                              hipStream_t stream)
{
    const float* y      = (const float*)d_in[0];
    const float* we1_w  = (const float*)d_in[1];  const float* we1_b  = (const float*)d_in[2];
    const float* we2_w  = (const float*)d_in[3];  const float* we2_b  = (const float*)d_in[4];
    const float* wfy1_w = (const float*)d_in[5];  const float* wfy1_b = (const float*)d_in[6];
    const float* wiy1_w = (const float*)d_in[7];  const float* wiy1_b = (const float*)d_in[8];
    const float* wfy2_w = (const float*)d_in[9];  const float* wfy2_b = (const float*)d_in[10];
    const float* wiy2_w = (const float*)d_in[11]; const float* wiy2_b = (const float*)d_in[12];
    const float* wd1_w  = (const float*)d_in[13]; const float* wd1_b  = (const float*)d_in[14];
    const float* wd2_w  = (const float*)d_in[15]; const float* wd2_b  = (const float*)d_in[16];
    const float* wfx1_w = (const float*)d_in[17]; const float* wfx1_b = (const float*)d_in[18];
    const float* wix1_w = (const float*)d_in[19]; const float* wix1_b = (const float*)d_in[20];
    const float* wfx2_w = (const float*)d_in[21]; const float* wfx2_b = (const float*)d_in[22];
    const float* wix2_w = (const float*)d_in[23]; const float* wix2_b = (const float*)d_in[24];
    const float* line_w1 = (const float*)d_in[25]; const float* line_b1 = (const float*)d_in[26];
    const float* line_w2 = (const float*)d_in[27]; const float* line_b2 = (const float*)d_in[28];
    const float* line_w3 = (const float*)d_in[29]; const float* line_b3 = (const float*)d_in[30];
    float* out = (float*)d_out;

    char* base = (char*)d_ws;
    size_t off = 0;
    auto take = [&](size_t bytes) -> void* {
        void* r = base + off;
        off += (bytes + 255) & ~(size_t)255;
        return r;
    };
    char* chunk_base = base;
    f16*   enc  = (f16*)take((size_t)6 * CHPX * KP * sizeof(f16));   // 39.8 MB
    f16*   xa   = (f16*)take((size_t)CHPX * KP * sizeof(f16));       //  6.6 MB
    f16*   xb   = (f16*)take((size_t)CHPX * KP * sizeof(f16));       //  6.6 MB
    float* cbuf = (float*)take((size_t)CHPX * KP * sizeof(float));   // 13.3 MB
    f16* xt1full = (f16*)take((size_t)NP * KP * sizeof(f16));        // 53.1 MB
    f16* wpk2 = (f16*)take((size_t)3 * KP * KP * sizeof(f16));
    f16* wpk1 = (f16*)take((size_t)3 * KP * KP * sizeof(f16));
    float* bpk2 = (float*)take((size_t)3 * KP * sizeof(float));
    float* bpk1 = (float*)take((size_t)3 * KP * sizeof(float));
    f16* w1p = (f16*)take((size_t)9 * OC * KP * sizeof(f16));
    f16* w2p = (f16*)take((size_t)OC * OC * sizeof(f16));
    f16* h1 = (f16*)chunk_base;
    f16* h2 = (f16*)(chunk_base + (size_t)NP2 * OC * sizeof(f16));
    if (off > ws_size) return;   // ~122 MB required; fail loudly via absmax

    pack_gate_w<<<2*3*KP, 64, 0, stream>>>(wd2_w, wfx2_w, wix2_w, wd1_w, wfx1_w, wix1_w,
                                           wd2_b, wfx2_b, wix2_b, wd1_b, wfx1_b, wix1_b,
                                           wpk2, wpk1, bpk2, bpk1);
    pack_line_w<<<9*OC + OC, 64, 0, stream>>>(line_w1, line_w2, w1p, w2p);

    const int EGRID = ((CHPX + 255) / 256) * NOC;   // 615
    const int GGRID = ((CHPX + 255) / 256) * 10;    // 41 n-blocks * 10 mt = 410
    f16* e0 = enc + (size_t)0*CHPX*KP;  // ywe1
    f16* e1 = enc + (size_t)1*CHPX*KP;  // ywe2
    f16* e2 = enc + (size_t)2*CHPX*KP;  // ywfy1
    f16* e3 = enc + (size_t)3*CHPX*KP;  // ywiy1
    f16* e4 = enc + (size_t)4*CHPX*KP;  // ywfy2
    f16* e5 = enc + (size_t)5*CHPX*KP;  // ywiy2

    for (int c = 0; c < CH; ++c) {
        int p_off = c * CHPX;
        encoder_kernel<<<EGRID, 256, 0, stream>>>(y,
            we1_w, we1_b, we2_w, we2_b, wfy1_w, wfy1_b, wiy1_w, wiy1_b,
            wfy2_w, wfy2_b, wiy2_w, wiy2_b,
            enc, cbuf, xa, p_off);

        // step2 #1 (xt1 term == 0): xa -> xb
        gate_kernel<<<GGRID, 256, 0, stream>>>(xa, wpk2, bpk2, e1, e4, e5, xb, cbuf, xb, 1);
        for (int it = 0; it < 3; ++it) {
            // step1: xb -> xa  (add term = xb)
            gate_kernel<<<GGRID, 256, 0, stream>>>(xb, wpk1, bpk1, e0, e2, e3, xb, cbuf, xa, 0);
            // step2: xa -> xb (add term = xb); last one writes final xt1
            f16* xo = (it == 2) ? (xt1full + (size_t)p_off * KP) : xb;
            gate_kernel<<<GGRID, 256, 0, stream>>>(xa, wpk2, bpk2, e1, e4, e5, xb, cbuf, xo, 0);
        }
    }

    conv3_kernel<<<568*5, 256, 0, stream>>>(xt1full, w1p, line_b1, h1);
    gemm128_kernel<<<((NP2 + 127)/128) * 4, 256, 0, stream>>>(h1, w2p, line_b2, h2);
    final_dot_kernel<<<(NP2 + 255)/256, 256, 0, stream>>>(h2, line_w3, line_b3, out);
}

// Round 5
// 2271.376 us; speedup vs baseline: 4.3216x; 1.3550x over previous
//
#include <hip/hip_runtime.h>

typedef _Float16 f16;
typedef _Float16 f16x8 __attribute__((ext_vector_type(8)));
typedef _Float16 f16x4 __attribute__((ext_vector_type(4)));
typedef float    f32x4 __attribute__((ext_vector_type(4)));

#define NP      82944     // 4*144*144 pixels
#define NPIX_B  20736     // 144*144
#define KP      320       // padded channel dim (300 -> 320)
#define OC      128       // 2*HID
#define NP2     80656     // 4*142*142 head pixels
#define NOC     15        // encoder o-chunks
#define OCH     20        // outputs per o-chunk (15*20 = 300)

__device__ __forceinline__ float geluf(float x) {
    return 0.5f * x * (1.0f + erff(x * 0.70710678118654752f));
}
__device__ __forceinline__ float sigm(float x) {
    return 1.0f / (1.0f + __expf(-x));
}
__device__ __forceinline__ f32x4 mfma16(f16x8 a, f16x8 b, f32x4 c) {
    return __builtin_amdgcn_mfma_f32_16x16x32_f16(a, b, c, 0, 0, 0);
}
__device__ __forceinline__ void gload_lds16(const void* g, void* l) {
    __builtin_amdgcn_global_load_lds(
        (const __attribute__((address_space(1))) void*)g,
        (__attribute__((address_space(3))) void*)l, 16, 0, 0);
}
// bijective XCD-chunked remap (m204): round-robin bid -> chunked lid so each
// XCD's L2 serves a contiguous range of logical tiles.
__device__ __forceinline__ int xcd_swz(int bid, int nwg) {
    int q = nwg >> 3, r = nwg & 7;
    int xcd = bid & 7, idx = bid >> 3;
    return (xcd < r ? xcd * (q + 1) : r * (q + 1) + (xcd - r) * q) + idx;
}

// ---------------- weight packing ----------------
__global__ __launch_bounds__(64) void pack_gate_w(
    const float* __restrict__ wd2, const float* __restrict__ wfx2, const float* __restrict__ wix2,
    const float* __restrict__ wd1, const float* __restrict__ wfx1, const float* __restrict__ wix1,
    const float* __restrict__ bd2, const float* __restrict__ bfx2, const float* __restrict__ bix2,
    const float* __restrict__ bd1, const float* __restrict__ bfx1, const float* __restrict__ bix1,
    f16* __restrict__ wpk2, f16* __restrict__ wpk1,
    float* __restrict__ bpk2, float* __restrict__ bpk1)
{
    int bid = blockIdx.x;                 // [0, 2*3*320)
    int o = bid % KP;
    int g = (bid / KP) % 3;
    int s = bid / (KP * 3);
    const float* wsrc; const float* bsrc;
    if (s == 0) { wsrc = (g==0)?wd2:((g==1)?wfx2:wix2); bsrc = (g==0)?bd2:((g==1)?bfx2:bix2); }
    else        { wsrc = (g==0)?wd1:((g==1)?wfx1:wix1); bsrc = (g==0)?bd1:((g==1)?bfx1:bix1); }
    f16* wdst = (s==0 ? wpk2 : wpk1) + ((size_t)g*KP + o)*KP;
    int t = threadIdx.x;
#pragma unroll
    for (int i = 0; i < 5; ++i) {
        int k = i*64 + t;
        wdst[k] = (o < 300 && k < 300) ? (f16)wsrc[o*300 + k] : (f16)0.0f;
    }
    if (t == 0) {
        float* bd = (s==0 ? bpk2 : bpk1);
        bd[g*KP + o] = (o < 300) ? bsrc[o] : 0.0f;
    }
}

__global__ __launch_bounds__(64) void pack_line_w(
    const float* __restrict__ lw1, const float* __restrict__ lw2,
    f16* __restrict__ w1p, f16* __restrict__ w2p)
{
    int bid = blockIdx.x;
    int t = threadIdx.x;
    if (bid < 9*OC) {
        int t9 = bid / OC, oc = bid % OC;
        f16* dst = w1p + ((size_t)t9*OC + oc)*KP;
#pragma unroll
        for (int i = 0; i < 5; ++i) {
            int k = i*64 + t;
            dst[k] = (k < 300) ? (f16)lw1[(size_t)(oc*300 + k)*9 + t9] : (f16)0.0f;
        }
    } else {
        int oc = bid - 9*OC;
        f16* dst = w2p + (size_t)oc*OC;
#pragma unroll
        for (int i = 0; i < 2; ++i) {
            int k = i*64 + t;
            dst[k] = (f16)lw2[oc*OC + k];
        }
    }
}

// ---------------- encoder (per chunk, o-split) ----------------
__global__ __launch_bounds__(256) void encoder_kernel(
    const float* __restrict__ y,
    const float* __restrict__ w_e1, const float* __restrict__ b_e1,
    const float* __restrict__ w_e2, const float* __restrict__ b_e2,
    const float* __restrict__ w_f1, const float* __restrict__ b_f1,
    const float* __restrict__ w_i1, const float* __restrict__ b_i1,
    const float* __restrict__ w_f2, const float* __restrict__ b_f2,
    const float* __restrict__ w_i2, const float* __restrict__ b_i2,
    f16* __restrict__ enc, float* __restrict__ cbuf, f16* __restrict__ xa,
    int p_off, int chpx)
{
    int lid = xcd_swz(blockIdx.x, gridDim.x);
    int oc = lid % NOC;
    int pb = lid / NOC;
    int p  = pb * 256 + threadIdx.x;
    if (p >= chpx) return;
    int o0 = oc * OCH;
    int gp = p_off + p;
    int b = gp / NPIX_B, pin = gp % NPIX_B;
    const float* yb = y + (size_t)b*21*NPIX_B + pin;
    float yv[21];
#pragma unroll
    for (int c = 0; c < 21; ++c) yv[c] = yb[(size_t)c * NPIX_B];

    size_t rowbase = (size_t)p*KP + o0;
    size_t estr = (size_t)chpx*KP;

#define ENC_ONE(W, B, EIDX)                                            \
    {                                                                  \
        f16* dst = enc + (size_t)(EIDX)*estr + rowbase;                \
        _Pragma("unroll 1")                                            \
        for (int rq = 0; rq < 5; ++rq) {                               \
            f16x4 st;                                                  \
            _Pragma("unroll")                                          \
            for (int j = 0; j < 4; ++j) {                              \
                int r = rq*4 + j;                                      \
                const float* wr = (W) + (o0 + r)*21;                   \
                float acc = (B)[o0 + r];                               \
                _Pragma("unroll")                                      \
                for (int c = 0; c < 21; ++c) acc = fmaf(wr[c], yv[c], acc); \
                st[j] = (f16)geluf(acc);                               \
            }                                                          \
            *(f16x4*)(dst + rq*4) = st;                                \
        }                                                              \
    }

    ENC_ONE(w_e1, b_e1, 0)
    ENC_ONE(w_e2, b_e2, 1)
    ENC_ONE(w_f1, b_f1, 2)
    ENC_ONE(w_i1, b_i1, 3)
    ENC_ONE(w_f2, b_f2, 4)
    ENC_ONE(w_i2, b_i2, 5)
#undef ENC_ONE

#pragma unroll 1
    for (int rq = 0; rq < 5; ++rq) {
        f16x4 v0 = *(const f16x4*)(enc + (size_t)0*estr + rowbase + rq*4);
        f16x4 v3 = *(const f16x4*)(enc + (size_t)3*estr + rowbase + rq*4);
        f32x4 cv; f16x4 xv;
#pragma unroll
        for (int j = 0; j < 4; ++j) {
            float c12 = sigm((float)v3[j]) * (-(float)v0[j]);
            cv[j] = c12;
            xv[j] = (f16)fmaxf(c12, 0.0f);
        }
        *(f32x4*)(cbuf + rowbase + rq*4) = cv;
        *(f16x4*)(xa + rowbase + rq*4) = xv;
    }
}

// ---------------- fused gate half-step: LDS double-buffered MFMA GEMM ----
// Tile: 96 A-rows (3 gates x 32 o) x 256 px, BK=32, 10 ksteps.
__global__ __launch_bounds__(256) void gate_kernel(
    const f16* __restrict__ xin, const f16* __restrict__ wpk,
    const float* __restrict__ bpk,
    const f16* __restrict__ ey, const f16* __restrict__ fy,
    const f16* __restrict__ iy, const f16* __restrict__ ad,
    float* __restrict__ cio, f16* __restrict__ xout, int first, int chpx)
{
    __shared__ char smem[2][28160];
    int tid = threadIdx.x;
    int l = tid & 63, w = tid >> 6;
    int lr = l & 15, lh = l >> 4;
    int lid = xcd_swz(blockIdx.x, gridDim.x);
    int mt = lid % 10, nt = lid / 10;
    int o0 = mt * 32;
    int p0 = nt * 256;

    // per-thread staging source pointers (k0=0); advance by 64B per kstep
    const char* srcb[7];
#pragma unroll
    for (int j = 0; j < 7; ++j) {
        int c = j*256 + tid;
        if (c < 480) {
            int row = c / 5, slot = c % 5; if (slot > 3) slot = 0;
            int g = row >> 5, o = o0 + (row & 31);
            srcb[j] = (const char*)wpk + ((size_t)g*KP + o)*(KP*2) + slot*16;
        } else if (c < 1760) {
            int cb = c - 480;
            int row = cb / 5, slot = cb % 5; if (slot > 3) slot = 0;
            int p = p0 + row; if (p > chpx-1) p = chpx-1;
            srcb[j] = (const char*)xin + (size_t)p*(KP*2) + slot*16;
        } else srcb[j] = nullptr;
    }

#define GSTAGE(BUF, KS)                                                \
    {                                                                  \
        int kb = (KS)*64;                                              \
        _Pragma("unroll")                                              \
        for (int j = 0; j < 7; ++j) {                                  \
            int c = j*256 + tid;                                       \
            if (c < 1760)                                              \
                gload_lds16(srcb[j] + kb, &smem[BUF][c*16]);           \
        }                                                              \
    }

    f32x4 acc[3][2][4] = {};
    GSTAGE(0, 0)
    __syncthreads();

    int buf = 0;
#pragma unroll 1
    for (int ks = 0; ks < 10; ++ks) {
        if (ks < 9) { GSTAGE(buf^1, ks+1) }
        f16x8 bfr[4];
#pragma unroll
        for (int n = 0; n < 4; ++n)
            bfr[n] = *(const f16x8*)&smem[buf][7680 + (w*64 + n*16 + lr)*80 + lh*16];
#pragma unroll
        for (int g = 0; g < 3; ++g) {
#pragma unroll
            for (int m = 0; m < 2; ++m) {
                f16x8 a = *(const f16x8*)&smem[buf][(g*32 + m*16 + lr)*80 + lh*16];
#pragma unroll
                for (int n = 0; n < 4; ++n)
                    acc[g][m][n] = mfma16(a, bfr[n], acc[g][m][n]);
            }
        }
        __syncthreads();
        buf ^= 1;
    }

#pragma unroll
    for (int m = 0; m < 2; ++m) {
        int o = o0 + m*16 + lh*4;
        if (o >= 300) continue;
        f32x4 bd = *(const f32x4*)(bpk + 0*KP + o);
        f32x4 bf = *(const f32x4*)(bpk + 1*KP + o);
        f32x4 bi = *(const f32x4*)(bpk + 2*KP + o);
#pragma unroll
        for (int n = 0; n < 4; ++n) {
            int p = p0 + w*64 + n*16 + lr;
            if (p >= chpx) continue;
            size_t base = (size_t)p*KP + o;
            f16x4 vey = *(const f16x4*)(ey + base);
            f16x4 vfy = *(const f16x4*)(fy + base);
            f16x4 viy = *(const f16x4*)(iy + base);
            f32x4 vci = *(const f32x4*)(cio + base);
            f16x4 vad = {};
            if (!first) vad = *(const f16x4*)(ad + base);
            f32x4 co; f16x4 xo;
#pragma unroll
            for (int r = 0; r < 4; ++r) {
                float gd = geluf(acc[0][m][n][r] + bd[r]);
                float gf = geluf(acc[1][m][n][r] + bf[r]);
                float gi = geluf(acc[2][m][n][r] + bi[r]);
                float addv = first ? 0.0f : (float)vad[r];
                float ctl = (float)vey[r] + addv - gd;
                float ft  = sigm(gf + (float)vfy[r]);
                float it  = sigm(gi + (float)viy[r]);
                float ct  = vci[r]*ft + ctl*it;
                co[r] = ct;
                xo[r] = (f16)fmaxf(ct, 0.0f);
            }
            *(f32x4*)(cio + base) = co;
            *(f16x4*)(xout + base) = xo;
        }
    }
#undef GSTAGE
}

// ---------------- head: 3x3 valid conv (LDS-staged input strip) ----------
__global__ __launch_bounds__(256) void conv3_kernel(
    const f16* __restrict__ xt, const f16* __restrict__ w1p,
    const float* __restrict__ b1, f16* __restrict__ h1)
{
    __shared__ char smem[96*656];   // 62.98 KB
    int tid = threadIdx.x;
    int l = tid & 63, w = tid >> 6;
    int lr = l & 15, lh = l >> 4;
    int lid = xcd_swz(blockIdx.x, gridDim.x);
    int xt5 = lid % 5;
    int by  = lid / 5;              // [0, 568)
    int b = by / 142, yy = by % 142;
    int xw = xt5 * 30;

    // stage 96 rows x 640B
#pragma unroll
    for (int j = 0; j < 16; ++j) {
        int c = j*256 + tid;
        if (c < 3936) {
            int lrow = c / 41, slot = c % 41; if (slot > 39) slot = 39;
            int dy = lrow >> 5, pxo = lrow & 31;
            int gx = xw + pxo; if (gx > 143) gx = 143;
            size_t gp = (size_t)((b*144 + yy + dy)*144 + gx);
            gload_lds16((const char*)xt + gp*(KP*2) + slot*16, &smem[0] + c*16);
        }
    }
    __syncthreads();

    f32x4 acc[2][2] = {};
#pragma unroll 1
    for (int t9 = 0; t9 < 9; ++t9) {
        int dy = t9 / 3, dx = t9 % 3;
        int r0 = dy*32 + dx + lr;        // n=0 row
        int r1 = r0 + 16;                // n=1 row
        if (r1 > 95) r1 = 95;            // clamp (only invalid outputs affected)
        const f16* ap = w1p + ((size_t)(t9*OC + w*32 + lr))*KP + lh*8;
#pragma unroll
        for (int k0 = 0; k0 < KP; k0 += 32) {
            int kb = (k0>>3)*16 + lh*16;
            f16x8 b0 = *(const f16x8*)&smem[r0*656 + kb];
            f16x8 b1 = *(const f16x8*)&smem[r1*656 + kb];
            f16x8 a0 = *(const f16x8*)(ap + k0);
            f16x8 a1 = *(const f16x8*)(ap + (size_t)16*KP + k0);
            acc[0][0] = mfma16(a0, b0, acc[0][0]);
            acc[0][1] = mfma16(a0, b1, acc[0][1]);
            acc[1][0] = mfma16(a1, b0, acc[1][0]);
            acc[1][1] = mfma16(a1, b1, acc[1][1]);
        }
    }
#pragma unroll
    for (int m = 0; m < 2; ++m) {
        int ocb = w*32 + m*16 + lh*4;
        f32x4 bb = *(const f32x4*)(b1 + ocb);
#pragma unroll
        for (int n = 0; n < 2; ++n) {
            int rel = n*16 + lr;
            int x = xw + rel;
            if (rel < 30 && x < 142) {
                int pout = (b*142 + yy)*142 + x;
                f16x4 hv;
#pragma unroll
                for (int r = 0; r < 4; ++r) hv[r] = (f16)geluf(acc[m][n][r] + bb[r]);
                *(f16x4*)(h1 + (size_t)pout*OC + ocb) = hv;
            }
        }
    }
}

// ---------------- head: 1x1 (128->128) + gelu ----------------
__global__ __launch_bounds__(256) void gemm128_kernel(
    const f16* __restrict__ hin, const f16* __restrict__ w2p,
    const float* __restrict__ b2, f16* __restrict__ hout)
{
    int tid = threadIdx.x;
    int l = tid & 63, w = tid >> 6;
    int lr = l & 15, lh = l >> 4;
    int bid = blockIdx.x;
    int mt = bid & 3, nt = bid >> 2;
    int p0 = nt * 128 + w * 32;
    if (p0 >= NP2) return;
    int o0 = mt * 32;

    f32x4 acc[2][2] = {};
    int pr0 = min(p0 + lr,      NP2 - 1);
    int pr1 = min(p0 + 16 + lr, NP2 - 1);
    const f16* bp0 = hin + (size_t)pr0*OC + lh*8;
    const f16* bp1 = hin + (size_t)pr1*OC + lh*8;
    const f16* ap  = w2p + (size_t)(o0 + lr)*OC + lh*8;
#pragma unroll
    for (int k0 = 0; k0 < OC; k0 += 32) {
        f16x8 b0  = *(const f16x8*)(bp0 + k0);
        f16x8 b1v = *(const f16x8*)(bp1 + k0);
#pragma unroll
        for (int m = 0; m < 2; ++m) {
            f16x8 a = *(const f16x8*)(ap + (size_t)m*16*OC + k0);
            acc[m][0] = mfma16(a, b0,  acc[m][0]);
            acc[m][1] = mfma16(a, b1v, acc[m][1]);
        }
    }
#pragma unroll
    for (int m = 0; m < 2; ++m) {
        int oc = o0 + m*16 + lh*4;
        f32x4 bb = *(const f32x4*)(b2 + oc);
#pragma unroll
        for (int n = 0; n < 2; ++n) {
            int p = p0 + n*16 + lr;
            if (p < NP2) {
                f16x4 hv;
#pragma unroll
                for (int r = 0; r < 4; ++r) hv[r] = (f16)geluf(acc[m][n][r] + bb[r]);
                *(f16x4*)(hout + (size_t)p*OC + oc) = hv;
            }
        }
    }
}

// ---------------- head: 1x1 (128->1) ----------------
__global__ __launch_bounds__(256) void final_dot_kernel(
    const f16* __restrict__ h2, const float* __restrict__ w3,
    const float* __restrict__ b3, float* __restrict__ out)
{
    int p = blockIdx.x * 256 + threadIdx.x;
    if (p >= NP2) return;
    const f16x8* row = (const f16x8*)(h2 + (size_t)p * OC);
    float acc = 0.0f;
#pragma unroll
    for (int i = 0; i < 16; ++i) {
        f16x8 v = row[i];
#pragma unroll
        for (int j = 0; j < 8; ++j) acc = fmaf((float)v[j], w3[i*8 + j], acc);
    }
    out[p] = acc + b3[0];
}

// ---------------- launch ----------------
extern "C" void kernel_launch(void* const* d_in, const int* in_sizes, int n_in,
                              void* d_out, int out_size, void* d_ws, size_t ws_size,
                              hipStream_t stream)
{
    const float* y      = (const float*)d_in[0];
    const float* we1_w  = (const float*)d_in[1];  const float* we1_b  = (const float*)d_in[2];
    const float* we2_w  = (const float*)d_in[3];  const float* we2_b  = (const float*)d_in[4];
    const float* wfy1_w = (const float*)d_in[5];  const float* wfy1_b = (const float*)d_in[6];
    const float* wiy1_w = (const float*)d_in[7];  const float* wiy1_b = (const float*)d_in[8];
    const float* wfy2_w = (const float*)d_in[9];  const float* wfy2_b = (const float*)d_in[10];
    const float* wiy2_w = (const float*)d_in[11]; const float* wiy2_b = (const float*)d_in[12];
    const float* wd1_w  = (const float*)d_in[13]; const float* wd1_b  = (const float*)d_in[14];
    const float* wd2_w  = (const float*)d_in[15]; const float* wd2_b  = (const float*)d_in[16];
    const float* wfx1_w = (const float*)d_in[17]; const float* wfx1_b = (const float*)d_in[18];
    const float* wix1_w = (const float*)d_in[19]; const float* wix1_b = (const float*)d_in[20];
    const float* wfx2_w = (const float*)d_in[21]; const float* wfx2_b = (const float*)d_in[22];
    const float* wix2_w = (const float*)d_in[23]; const float* wix2_b = (const float*)d_in[24];
    const float* line_w1 = (const float*)d_in[25]; const float* line_b1 = (const float*)d_in[26];
    const float* line_w2 = (const float*)d_in[27]; const float* line_b2 = (const float*)d_in[28];
    const float* line_w3 = (const float*)d_in[29]; const float* line_b3 = (const float*)d_in[30];
    float* out = (float*)d_out;

    // adaptive chunking: CH=4 (bigger grid, fewer dispatches) if workspace
    // allows (~188 MB), else proven CH=8 path (~122 MB).
    auto padb = [](size_t b){ return (b + 255) & ~(size_t)255; };
    auto need = [&](int ch)->size_t {
        size_t chpx = (size_t)NP / ch;
        size_t s = 0;
        s += padb(6*chpx*KP*2);            // enc
        s += 2*padb(chpx*KP*2);            // xa, xb
        s += padb(chpx*KP*4);              // cbuf
        s += padb((size_t)NP*KP*2);        // xt1full
        s += 2*padb((size_t)3*KP*KP*2);    // wpk2, wpk1
        s += 2*padb((size_t)3*KP*4);       // bpk2, bpk1
        s += padb((size_t)9*OC*KP*2);      // w1p
        s += padb((size_t)OC*OC*2);        // w2p
        return s;
    };
    const int CHN = (need(4) <= ws_size) ? 4 : 8;
    const int chpx = NP / CHN;

    char* base = (char*)d_ws;
    size_t off = 0;
    auto take = [&](size_t bytes) -> void* {
        void* r = base + off;
        off += (bytes + 255) & ~(size_t)255;
        return r;
    };
    char* chunk_base = base;
    f16*   enc  = (f16*)take((size_t)6 * chpx * KP * sizeof(f16));
    f16*   xa   = (f16*)take((size_t)chpx * KP * sizeof(f16));
    f16*   xb   = (f16*)take((size_t)chpx * KP * sizeof(f16));
    float* cbuf = (float*)take((size_t)chpx * KP * sizeof(float));
    f16* xt1full = (f16*)take((size_t)NP * KP * sizeof(f16));
    f16* wpk2 = (f16*)take((size_t)3 * KP * KP * sizeof(f16));
    f16* wpk1 = (f16*)take((size_t)3 * KP * KP * sizeof(f16));
    float* bpk2 = (float*)take((size_t)3 * KP * sizeof(float));
    float* bpk1 = (float*)take((size_t)3 * KP * sizeof(float));
    f16* w1p = (f16*)take((size_t)9 * OC * KP * sizeof(f16));
    f16* w2p = (f16*)take((size_t)OC * OC * sizeof(f16));
    f16* h1 = (f16*)chunk_base;   // alias dead chunk region for the head
    f16* h2 = (f16*)(chunk_base + (size_t)NP2 * OC * sizeof(f16));
    if (off > ws_size) return;    // fail loudly via absmax

    pack_gate_w<<<2*3*KP, 64, 0, stream>>>(wd2_w, wfx2_w, wix2_w, wd1_w, wfx1_w, wix1_w,
                                           wd2_b, wfx2_b, wix2_b, wd1_b, wfx1_b, wix1_b,
                                           wpk2, wpk1, bpk2, bpk1);
    pack_line_w<<<9*OC + OC, 64, 0, stream>>>(line_w1, line_w2, w1p, w2p);

    const int EGRID = ((chpx + 255) / 256) * NOC;
    const int GGRID = ((chpx + 255) / 256) * 10;
    f16* e0 = enc + (size_t)0*chpx*KP;  // ywe1
    f16* e1 = enc + (size_t)1*chpx*KP;  // ywe2
    f16* e2 = enc + (size_t)2*chpx*KP;  // ywfy1
    f16* e3 = enc + (size_t)3*chpx*KP;  // ywiy1
    f16* e4 = enc + (size_t)4*chpx*KP;  // ywfy2
    f16* e5 = enc + (size_t)5*chpx*KP;  // ywiy2

    for (int c = 0; c < CHN; ++c) {
        int p_off = c * chpx;
        encoder_kernel<<<EGRID, 256, 0, stream>>>(y,
            we1_w, we1_b, we2_w, we2_b, wfy1_w, wfy1_b, wiy1_w, wiy1_b,
            wfy2_w, wfy2_b, wiy2_w, wiy2_b,
            enc, cbuf, xa, p_off, chpx);

        // step2 #1 (xt1 term == 0): xa -> xb
        gate_kernel<<<GGRID, 256, 0, stream>>>(xa, wpk2, bpk2, e1, e4, e5, xb, cbuf, xb, 1, chpx);
        for (int it = 0; it < 3; ++it) {
            // step1: xb -> xa  (add term = xb)
            gate_kernel<<<GGRID, 256, 0, stream>>>(xb, wpk1, bpk1, e0, e2, e3, xb, cbuf, xa, 0, chpx);
            // step2: xa -> xb (add term = xb); last one writes final xt1
            f16* xo = (it == 2) ? (xt1full + (size_t)p_off * KP) : xb;
            gate_kernel<<<GGRID, 256, 0, stream>>>(xa, wpk2, bpk2, e1, e4, e5, xb, cbuf, xo, 0, chpx);
        }
    }

    conv3_kernel<<<568*5, 256, 0, stream>>>(xt1full, w1p, line_b1, h1);
    gemm128_kernel<<<((NP2 + 127)/128) * 4, 256, 0, stream>>>(h1, w2p, line_b2, h2);
    final_dot_kernel<<<(NP2 + 255)/256, 256, 0, stream>>>(h2, line_w3, line_b3, out);
}